// Round 1
// baseline (2225.638 us; speedup 1.0000x reference)
//
#include <hip/hip_runtime.h>
#include <math.h>

#define NN 100000
#define NE 1600000
#define IND 128
#define OUTD 64
#define ED 16
#define NH 4
#define HD 16

static __device__ __forceinline__ void atomicMaxFloat(unsigned int* addr, float v) {
    // works for mixed-sign floats: int-max for >=0, unsigned-min for <0
    if (v >= 0.f) atomicMax((int*)addr, __float_as_int(v));
    else          atomicMin(addr, (unsigned int)__float_as_int(v));
}

// ---------------- init: zero out + den, set gmax = -inf ----------------
__global__ void k_init(float* __restrict__ out, float* __restrict__ den,
                       unsigned int* __restrict__ gmax) {
    int i = blockIdx.x * blockDim.x + threadIdx.x;
    int stride = gridDim.x * blockDim.x;
    float4 z = make_float4(0.f, 0.f, 0.f, 0.f);
    for (int j = i; j < NN * (OUTD / 4); j += stride) ((float4*)out)[j] = z;
    for (int j = i; j < NN; j += stride) ((float4*)den)[j] = z;  // NN float4 = NN*4 floats
    if (i == 0) *gmax = 0xFF800000u;  // -inf bits
}

// ---------------- node GEMM + attention scalars ----------------
// Wh = x @ Wn^T  [NN,64]; asrc/adst = per-(node,head) dots with att vectors.
// 16 rows per block (4 per wave); W transposed in LDS [k][c] (2-way bank alias = free).
__global__ __launch_bounds__(256) void k_node(
        const float* __restrict__ x, const float* __restrict__ Wn,
        const float* __restrict__ att_s, const float* __restrict__ att_d,
        float* __restrict__ Wh, float* __restrict__ asrc, float* __restrict__ adst) {
    __shared__ float sWt[IND * OUTD];   // 32 KB, [k][c]
    __shared__ float sx[16][IND];       // 8 KB
    int tid = threadIdx.x;

    // load W transposed: thread -> (c = tid&63, k4 = tid>>6 stepping by 4)
    {
        int c = tid & 63;
        for (int k4 = tid >> 6; k4 < IND / 4; k4 += 4) {
            float4 v = ((const float4*)Wn)[c * (IND / 4) + k4];
            sWt[(k4 * 4 + 0) * OUTD + c] = v.x;
            sWt[(k4 * 4 + 1) * OUTD + c] = v.y;
            sWt[(k4 * 4 + 2) * OUTD + c] = v.z;
            sWt[(k4 * 4 + 3) * OUTD + c] = v.w;
        }
    }
    long long rowBase = (long long)blockIdx.x * 16;
    for (int i = tid; i < 16 * (IND / 4); i += 256) {
        int r = i >> 5, k4 = i & 31;
        long long row = rowBase + r;
        float4 v = make_float4(0.f, 0.f, 0.f, 0.f);
        if (row < NN) v = ((const float4*)x)[row * (IND / 4) + k4];
        ((float4*)sx)[r * (IND / 4) + k4] = v;
    }
    __syncthreads();

    int wave = tid >> 6, lane = tid & 63;
    float as = att_s[lane];  // [h*16+dim], lane==c mapping
    float ad = att_d[lane];
    for (int rr = 0; rr < 4; rr++) {
        long long row = rowBase + wave * 4 + rr;
        if (row >= NN) break;
        const float4* sx4 = (const float4*)&sx[wave * 4 + rr][0];
        float acc = 0.f;
#pragma unroll
        for (int k4 = 0; k4 < IND / 4; k4++) {
            float4 xv = sx4[k4];
            acc += xv.x * sWt[(k4 * 4 + 0) * OUTD + lane];
            acc += xv.y * sWt[(k4 * 4 + 1) * OUTD + lane];
            acc += xv.z * sWt[(k4 * 4 + 2) * OUTD + lane];
            acc += xv.w * sWt[(k4 * 4 + 3) * OUTD + lane];
        }
        Wh[row * OUTD + lane] = acc;
        float vs = acc * as, vd = acc * ad;
#pragma unroll
        for (int m = 1; m < 16; m <<= 1) {
            vs += __shfl_xor(vs, m);
            vd += __shfl_xor(vd, m);
        }
        if ((lane & 15) == 0) {
            int h = lane >> 4;
            asrc[row * NH + h] = vs;
            adst[row * NH + h] = vd;
        }
    }
}

// ---------------- edge scores + global max ----------------
__global__ __launch_bounds__(256) void k_edge(
        const int* __restrict__ ei, const float* __restrict__ ea,
        const float* __restrict__ We, const float* __restrict__ asrc,
        const float* __restrict__ adst, float* __restrict__ esc,
        unsigned int* __restrict__ gmax) {
    __shared__ float sWe[NH * ED];  // 64 floats
    if (threadIdx.x < NH * ED) sWe[threadIdx.x] = We[threadIdx.x];
    __syncthreads();
    int e = blockIdx.x * 256 + threadIdx.x;
    float lmax = -INFINITY;
    if (e < NE) {
        int s = ei[e], d = ei[NE + e];
        float4 as4 = *(const float4*)(asrc + (long long)s * NH);
        float4 ad4 = *(const float4*)(adst + (long long)d * NH);
        const float4* ea4 = (const float4*)(ea + (long long)e * ED);
        float4 e0 = ea4[0], e1 = ea4[1], e2 = ea4[2], e3 = ea4[3];
        float asv[4] = {as4.x, as4.y, as4.z, as4.w};
        float adv[4] = {ad4.x, ad4.y, ad4.z, ad4.w};
        float sc[4];
#pragma unroll
        for (int h = 0; h < NH; h++) {
            const float* w = sWe + h * ED;
            float t = asv[h] + adv[h];
            t += e0.x * w[0]  + e0.y * w[1]  + e0.z * w[2]  + e0.w * w[3];
            t += e1.x * w[4]  + e1.y * w[5]  + e1.z * w[6]  + e1.w * w[7];
            t += e2.x * w[8]  + e2.y * w[9]  + e2.z * w[10] + e2.w * w[11];
            t += e3.x * w[12] + e3.y * w[13] + e3.z * w[14] + e3.w * w[15];
            t = (t >= 0.f) ? t : 0.2f * t;  // leaky_relu 0.2
            sc[h] = t;
            lmax = fmaxf(lmax, t);
        }
        *(float4*)(esc + (long long)e * NH) = make_float4(sc[0], sc[1], sc[2], sc[3]);
    }
#pragma unroll
    for (int m = 1; m < 64; m <<= 1) lmax = fmaxf(lmax, __shfl_xor(lmax, m));
    if ((threadIdx.x & 63) == 0) atomicMaxFloat(gmax, lmax);
}

// ---------------- exp(e - gmax) + denominator segment-sum ----------------
__global__ __launch_bounds__(256) void k_den(
        const int* __restrict__ ei, float* __restrict__ esc,
        const unsigned int* __restrict__ gmax, float* __restrict__ den) {
    int e = blockIdx.x * 256 + threadIdx.x;
    if (e >= NE) return;
    float gm = __uint_as_float(*gmax);
    int d = ei[NE + e];
    float4 sc = *(float4*)(esc + (long long)e * NH);
    float4 ex = make_float4(expf(sc.x - gm), expf(sc.y - gm),
                            expf(sc.z - gm), expf(sc.w - gm));
    *(float4*)(esc + (long long)e * NH) = ex;
    float* dp = den + (long long)d * NH;
    atomicAdd(dp + 0, ex.x);
    atomicAdd(dp + 1, ex.y);
    atomicAdd(dp + 2, ex.z);
    atomicAdd(dp + 3, ex.w);
}

// ---------------- message scatter: out[d] += Wh[s] * alpha ----------------
// 16 threads per edge: thread t -> head h = t>>2, quad q = t&3 (4 channels)
__global__ __launch_bounds__(256) void k_msg(
        const int* __restrict__ ei, const float* __restrict__ esc,
        const float* __restrict__ den, const float* __restrict__ Wh,
        float* __restrict__ out) {
    long long gid = (long long)blockIdx.x * 256 + threadIdx.x;
    long long e = gid >> 4;
    if (e >= NE) return;
    int t = (int)(gid & 15);
    int h = t >> 2, q = t & 3;
    int s = ei[e], d = ei[NE + e];
    float ex = esc[e * NH + h];
    float dn = den[(long long)d * NH + h];
    float alpha = ex / (dn + 1e-9f);
    float4 w = *(const float4*)(Wh + (long long)s * OUTD + h * HD + q * 4);
    float* o = out + (long long)d * OUTD + h * HD + q * 4;
    atomicAdd(o + 0, w.x * alpha);
    atomicAdd(o + 1, w.y * alpha);
    atomicAdd(o + 2, w.z * alpha);
    atomicAdd(o + 3, w.w * alpha);
}

// ---------------- finalize: elu(acc + bias) in place ----------------
__global__ void k_fin(float* __restrict__ out, const float* __restrict__ bias) {
    int i = blockIdx.x * 256 + threadIdx.x;  // float4 index over NN*64
    if (i >= NN * (OUTD / 4)) return;
    float4 v = ((float4*)out)[i];
    int cb = (i & (OUTD / 4 - 1)) * 4;
    v.x += bias[cb + 0];
    v.y += bias[cb + 1];
    v.z += bias[cb + 2];
    v.w += bias[cb + 3];
    v.x = (v.x > 0.f) ? v.x : expm1f(v.x);
    v.y = (v.y > 0.f) ? v.y : expm1f(v.y);
    v.z = (v.z > 0.f) ? v.z : expm1f(v.z);
    v.w = (v.w > 0.f) ? v.w : expm1f(v.w);
    ((float4*)out)[i] = v;
}

extern "C" void kernel_launch(void* const* d_in, const int* in_sizes, int n_in,
                              void* d_out, int out_size, void* d_ws, size_t ws_size,
                              hipStream_t stream) {
    const float* x     = (const float*)d_in[0];   // [NN,128]
    const int*   ei    = (const int*)d_in[1];     // [2,NE]
    const float* ea    = (const float*)d_in[2];   // [NE,16]
    const float* Wn    = (const float*)d_in[3];   // [64,128]
    const float* We    = (const float*)d_in[4];   // [4,16]
    const float* att_s = (const float*)d_in[5];   // [1,4,16] -> 64
    const float* att_d = (const float*)d_in[6];   // 64
    const float* bias  = (const float*)d_in[7];   // 64
    float* out = (float*)d_out;

    float* ws   = (float*)d_ws;
    float* Wh   = ws;                                  // NN*64
    float* asrc = Wh + (size_t)NN * OUTD;              // NN*4
    float* adst = asrc + (size_t)NN * NH;              // NN*4
    float* esc  = adst + (size_t)NN * NH;              // NE*4
    float* den  = esc + (size_t)NE * NH;               // NN*4
    unsigned int* gmax = (unsigned int*)(den + (size_t)NN * NH);

    k_init<<<1024, 256, 0, stream>>>(out, den, gmax);
    k_node<<<(NN + 15) / 16, 256, 0, stream>>>(x, Wn, att_s, att_d, Wh, asrc, adst);
    k_edge<<<(NE + 255) / 256, 256, 0, stream>>>(ei, ea, We, asrc, adst, esc, gmax);
    k_den<<<(NE + 255) / 256, 256, 0, stream>>>(ei, esc, gmax, den);
    k_msg<<<(int)(((long long)NE * 16 + 255) / 256), 256, 0, stream>>>(ei, esc, den, Wh, out);
    k_fin<<<(NN * (OUTD / 4) + 255) / 256, 256, 0, stream>>>(out, bias);
}

// Round 2
// 798.051 us; speedup vs baseline: 2.7888x; 2.7888x over previous
//
#include <hip/hip_runtime.h>
#include <math.h>

#define NN 100000
#define NE 1600000
#define IND 128
#define OUTD 64
#define ED 16
#define NH 4
#define HD 16
#define NB1 98   // ceil(NN/1024) for scan phase 1

static __device__ __forceinline__ void atomicMaxFloat(unsigned int* addr, float v) {
    if (v >= 0.f) atomicMax((int*)addr, __float_as_int(v));
    else          atomicMin(addr, (unsigned int)__float_as_int(v));
}

// ---------------- zero degree histogram, init gmax ----------------
__global__ void k_zero(int* __restrict__ deg, unsigned int* __restrict__ gmax) {
    int i = blockIdx.x * 256 + threadIdx.x;
    if (i < NN) deg[i] = 0;
    if (i == 0) *gmax = 0xFF800000u;  // -inf
}

// ---------------- node GEMM + attention scalars (unchanged from R1) --------
__global__ __launch_bounds__(256) void k_node(
        const float* __restrict__ x, const float* __restrict__ Wn,
        const float* __restrict__ att_s, const float* __restrict__ att_d,
        float* __restrict__ Wh, float* __restrict__ asrc, float* __restrict__ adst) {
    __shared__ float sWt[IND * OUTD];   // 32 KB, [k][c]
    __shared__ float sx[16][IND];       // 8 KB
    int tid = threadIdx.x;
    {
        int c = tid & 63;
        for (int k4 = tid >> 6; k4 < IND / 4; k4 += 4) {
            float4 v = ((const float4*)Wn)[c * (IND / 4) + k4];
            sWt[(k4 * 4 + 0) * OUTD + c] = v.x;
            sWt[(k4 * 4 + 1) * OUTD + c] = v.y;
            sWt[(k4 * 4 + 2) * OUTD + c] = v.z;
            sWt[(k4 * 4 + 3) * OUTD + c] = v.w;
        }
    }
    long long rowBase = (long long)blockIdx.x * 16;
    for (int i = tid; i < 16 * (IND / 4); i += 256) {
        int r = i >> 5, k4 = i & 31;
        long long row = rowBase + r;
        float4 v = make_float4(0.f, 0.f, 0.f, 0.f);
        if (row < NN) v = ((const float4*)x)[row * (IND / 4) + k4];
        ((float4*)sx)[r * (IND / 4) + k4] = v;
    }
    __syncthreads();

    int wave = tid >> 6, lane = tid & 63;
    float as = att_s[lane];
    float ad = att_d[lane];
    for (int rr = 0; rr < 4; rr++) {
        long long row = rowBase + wave * 4 + rr;
        if (row >= NN) break;
        const float4* sx4 = (const float4*)&sx[wave * 4 + rr][0];
        float acc = 0.f;
#pragma unroll
        for (int k4 = 0; k4 < IND / 4; k4++) {
            float4 xv = sx4[k4];
            acc += xv.x * sWt[(k4 * 4 + 0) * OUTD + lane];
            acc += xv.y * sWt[(k4 * 4 + 1) * OUTD + lane];
            acc += xv.z * sWt[(k4 * 4 + 2) * OUTD + lane];
            acc += xv.w * sWt[(k4 * 4 + 3) * OUTD + lane];
        }
        Wh[row * OUTD + lane] = acc;
        float vs = acc * as, vd = acc * ad;
#pragma unroll
        for (int m = 1; m < 16; m <<= 1) {
            vs += __shfl_xor(vs, m);
            vd += __shfl_xor(vd, m);
        }
        if ((lane & 15) == 0) {
            int h = lane >> 4;
            asrc[row * NH + h] = vs;
            adst[row * NH + h] = vd;
        }
    }
}

// ---------------- degree histogram ----------------
__global__ void k_hist(const int* __restrict__ ei, int* __restrict__ deg) {
    int e = blockIdx.x * 256 + threadIdx.x;
    if (e < NE) atomicAdd(&deg[ei[NE + e]], 1);
}

// ---------------- 3-phase exclusive scan over deg[NN] ----------------
__global__ __launch_bounds__(256) void k_scan1(const int* __restrict__ deg,
                                               int* __restrict__ offA,
                                               int* __restrict__ bsum) {
    __shared__ int sd[256];
    int b = blockIdx.x, t = threadIdx.x;
    int base = b * 1024 + t * 4;
    int v0 = 0, v1 = 0, v2 = 0, v3 = 0;
    if (base + 0 < NN) v0 = deg[base + 0];
    if (base + 1 < NN) v1 = deg[base + 1];
    if (base + 2 < NN) v2 = deg[base + 2];
    if (base + 3 < NN) v3 = deg[base + 3];
    int s = v0 + v1 + v2 + v3;
    sd[t] = s;
    __syncthreads();
    for (int ofs = 1; ofs < 256; ofs <<= 1) {
        int xv = 0;
        if (t >= ofs) xv = sd[t - ofs];
        __syncthreads();
        sd[t] += xv;
        __syncthreads();
    }
    int excl = sd[t] - s;
    if (base + 0 < NN) offA[base + 0] = excl;
    if (base + 1 < NN) offA[base + 1] = excl + v0;
    if (base + 2 < NN) offA[base + 2] = excl + v0 + v1;
    if (base + 3 < NN) offA[base + 3] = excl + v0 + v1 + v2;
    if (t == 255) bsum[b] = sd[255];
}

__global__ __launch_bounds__(128) void k_scan2(int* __restrict__ bsum) {
    __shared__ int sd[128];
    int t = threadIdx.x;
    int v = (t < NB1) ? bsum[t] : 0;
    sd[t] = v;
    __syncthreads();
    for (int ofs = 1; ofs < 128; ofs <<= 1) {
        int xv = 0;
        if (t >= ofs) xv = sd[t - ofs];
        __syncthreads();
        sd[t] += xv;
        __syncthreads();
    }
    if (t < NB1) bsum[t] = sd[t] - v;  // exclusive
}

__global__ void k_scan3(const int* __restrict__ offA, const int* __restrict__ bsum,
                        int* __restrict__ off, int* __restrict__ pos) {
    int i = blockIdx.x * 256 + threadIdx.x;
    if (i < NN) {
        int v = offA[i] + bsum[i >> 10];
        off[i] = v;
        pos[i] = v;
    }
    if (i == 0) off[NN] = NE;
}

// ---------------- edge scores + global max + CSR scatter ----------------
__global__ __launch_bounds__(256) void k_edge(
        const int* __restrict__ ei, const float* __restrict__ ea,
        const float* __restrict__ We, const float* __restrict__ asrc,
        const float* __restrict__ adst, int* __restrict__ pos,
        int* __restrict__ srcs, float* __restrict__ esc4,
        unsigned int* __restrict__ gmax) {
    __shared__ float sWe[NH * ED];
    if (threadIdx.x < NH * ED) sWe[threadIdx.x] = We[threadIdx.x];
    __syncthreads();
    int e = blockIdx.x * 256 + threadIdx.x;
    float lmax = -INFINITY;
    if (e < NE) {
        int s = ei[e], d = ei[NE + e];
        float4 as4 = *(const float4*)(asrc + (long long)s * NH);
        float4 ad4 = *(const float4*)(adst + (long long)d * NH);
        const float4* ea4 = (const float4*)(ea + (long long)e * ED);
        float4 e0 = ea4[0], e1 = ea4[1], e2 = ea4[2], e3 = ea4[3];
        float asv[4] = {as4.x, as4.y, as4.z, as4.w};
        float adv[4] = {ad4.x, ad4.y, ad4.z, ad4.w};
        float sc[4];
#pragma unroll
        for (int h = 0; h < NH; h++) {
            const float* w = sWe + h * ED;
            float t = asv[h] + adv[h];
            t += e0.x * w[0]  + e0.y * w[1]  + e0.z * w[2]  + e0.w * w[3];
            t += e1.x * w[4]  + e1.y * w[5]  + e1.z * w[6]  + e1.w * w[7];
            t += e2.x * w[8]  + e2.y * w[9]  + e2.z * w[10] + e2.w * w[11];
            t += e3.x * w[12] + e3.y * w[13] + e3.z * w[14] + e3.w * w[15];
            t = (t >= 0.f) ? t : 0.2f * t;
            sc[h] = t;
            lmax = fmaxf(lmax, t);
        }
        int p = atomicAdd(&pos[d], 1);
        srcs[p] = s;
        *(float4*)(esc4 + (long long)p * NH) = make_float4(sc[0], sc[1], sc[2], sc[3]);
    }
#pragma unroll
    for (int m = 1; m < 64; m <<= 1) lmax = fmaxf(lmax, __shfl_xor(lmax, m));
    if ((threadIdx.x & 63) == 0) atomicMaxFloat(gmax, lmax);
}

// ---------------- gather: per-node softmax + weighted accumulate + elu ------
// one wave per destination node; lane = output channel; h = lane>>4
__global__ __launch_bounds__(256) void k_gather(
        const int* __restrict__ off, const int* __restrict__ srcs,
        const float* __restrict__ esc4, const float* __restrict__ Wh,
        const unsigned int* __restrict__ gmax, const float* __restrict__ bias,
        float* __restrict__ out) {
    int node = blockIdx.x * 4 + (threadIdx.x >> 6);
    int lane = threadIdx.x & 63;
    if (node >= NN) return;
    int start = off[node], end = off[node + 1];
    float gm = __uint_as_float(*gmax);

    // pass 1: denominator (sum of exp over incoming edges), per head
    float4 dsum = make_float4(0.f, 0.f, 0.f, 0.f);
    for (int j = start + lane; j < end; j += 64) {
        float4 sc = ((const float4*)esc4)[j];
        dsum.x += expf(sc.x - gm);
        dsum.y += expf(sc.y - gm);
        dsum.z += expf(sc.z - gm);
        dsum.w += expf(sc.w - gm);
    }
#pragma unroll
    for (int m = 1; m < 64; m <<= 1) {
        dsum.x += __shfl_xor(dsum.x, m);
        dsum.y += __shfl_xor(dsum.y, m);
        dsum.z += __shfl_xor(dsum.z, m);
        dsum.w += __shfl_xor(dsum.w, m);
    }
    int h = lane >> 4;
    float den = (h == 0) ? dsum.x : (h == 1) ? dsum.y : (h == 2) ? dsum.z : dsum.w;
    float rden = 1.0f / (den + 1e-9f);

    // pass 2: accumulate alpha * Wh[s] into registers
    float acc = 0.f;
    for (int j = start; j < end; j++) {
        int s = srcs[j];
        float sc = esc4[j * 4 + h];
        acc += Wh[(long long)s * OUTD + lane] * (expf(sc - gm) * rden);
    }
    float v = acc + bias[lane];
    out[(long long)node * OUTD + lane] = (v > 0.f) ? v : expm1f(v);
}

extern "C" void kernel_launch(void* const* d_in, const int* in_sizes, int n_in,
                              void* d_out, int out_size, void* d_ws, size_t ws_size,
                              hipStream_t stream) {
    const float* x     = (const float*)d_in[0];   // [NN,128]
    const int*   ei    = (const int*)d_in[1];     // [2,NE]
    const float* ea    = (const float*)d_in[2];   // [NE,16]
    const float* Wn    = (const float*)d_in[3];   // [64,128]
    const float* We    = (const float*)d_in[4];   // [4,16]
    const float* att_s = (const float*)d_in[5];   // 64
    const float* att_d = (const float*)d_in[6];   // 64
    const float* bias  = (const float*)d_in[7];   // 64
    float* out = (float*)d_out;

    float* ws   = (float*)d_ws;
    float* Wh   = ws;                                   // NN*64 f
    float* asrc = Wh + (size_t)NN * OUTD;               // NN*4 f
    float* adst = asrc + (size_t)NN * NH;               // NN*4 f
    float* esc4 = adst + (size_t)NN * NH;               // NE*4 f (dest-sorted scores)
    int*   srcs = (int*)(esc4 + (size_t)NE * NH);       // NE i
    int*   deg  = srcs + (size_t)NE;                    // NN i
    int*   offA = deg + NN;                             // NN i
    int*   off  = offA + NN;                            // NN+1 i
    int*   pos  = off + NN + 1;                         // NN i
    int*   bsum = pos + NN;                             // 128 i
    unsigned int* gmax = (unsigned int*)(bsum + 128);   // 1

    k_zero<<<(NN + 255) / 256, 256, 0, stream>>>(deg, gmax);
    k_node<<<(NN + 15) / 16, 256, 0, stream>>>(x, Wn, att_s, att_d, Wh, asrc, adst);
    k_hist<<<(NE + 255) / 256, 256, 0, stream>>>(ei, deg);
    k_scan1<<<NB1, 256, 0, stream>>>(deg, offA, bsum);
    k_scan2<<<1, 128, 0, stream>>>(bsum);
    k_scan3<<<(NN + 255) / 256, 256, 0, stream>>>(offA, bsum, off, pos);
    k_edge<<<(NE + 255) / 256, 256, 0, stream>>>(ei, ea, We, asrc, adst, pos, srcs, esc4, gmax);
    k_gather<<<(NN + 3) / 4, 256, 0, stream>>>(off, srcs, esc4, Wh, gmax, bias, out);
}

// Round 3
// 614.102 us; speedup vs baseline: 3.6242x; 1.2995x over previous
//
#include <hip/hip_runtime.h>
#include <math.h>

#define NN 100000
#define NE 1600000
#define IND 128
#define OUTD 64
#define ED 16
#define NH 4
#define HD 16
#define NB1 98      // ceil(NN/1024) for scan phase 1
#define NSLOT 1024  // gmax reduction slots

static __device__ __forceinline__ void atomicMaxFloat(unsigned int* addr, float v) {
    if (v >= 0.f) atomicMax((int*)addr, __float_as_int(v));
    else          atomicMin(addr, (unsigned int)__float_as_int(v));
}

// ---------------- zero degree histogram, init gmax slots ----------------
__global__ void k_zero(int* __restrict__ deg, unsigned int* __restrict__ smax) {
    int i = blockIdx.x * 256 + threadIdx.x;
    if (i < NN) deg[i] = 0;
    if (i < NSLOT) smax[i] = 0xFF800000u;  // -inf
}

// ---------------- node GEMM + attention scalars --------
__global__ __launch_bounds__(256) void k_node(
        const float* __restrict__ x, const float* __restrict__ Wn,
        const float* __restrict__ att_s, const float* __restrict__ att_d,
        float* __restrict__ Wh, float* __restrict__ asrc, float* __restrict__ adst) {
    __shared__ float sWt[IND * OUTD];   // 32 KB, [k][c]
    __shared__ float sx[16][IND];       // 8 KB
    int tid = threadIdx.x;
    {
        int c = tid & 63;
        for (int k4 = tid >> 6; k4 < IND / 4; k4 += 4) {
            float4 v = ((const float4*)Wn)[c * (IND / 4) + k4];
            sWt[(k4 * 4 + 0) * OUTD + c] = v.x;
            sWt[(k4 * 4 + 1) * OUTD + c] = v.y;
            sWt[(k4 * 4 + 2) * OUTD + c] = v.z;
            sWt[(k4 * 4 + 3) * OUTD + c] = v.w;
        }
    }
    long long rowBase = (long long)blockIdx.x * 16;
    for (int i = tid; i < 16 * (IND / 4); i += 256) {
        int r = i >> 5, k4 = i & 31;
        long long row = rowBase + r;
        float4 v = make_float4(0.f, 0.f, 0.f, 0.f);
        if (row < NN) v = ((const float4*)x)[row * (IND / 4) + k4];
        ((float4*)sx)[r * (IND / 4) + k4] = v;
    }
    __syncthreads();

    int wave = tid >> 6, lane = tid & 63;
    float as = att_s[lane];
    float ad = att_d[lane];
    for (int rr = 0; rr < 4; rr++) {
        long long row = rowBase + wave * 4 + rr;
        if (row >= NN) break;
        const float4* sx4 = (const float4*)&sx[wave * 4 + rr][0];
        float acc = 0.f;
#pragma unroll
        for (int k4 = 0; k4 < IND / 4; k4++) {
            float4 xv = sx4[k4];
            acc += xv.x * sWt[(k4 * 4 + 0) * OUTD + lane];
            acc += xv.y * sWt[(k4 * 4 + 1) * OUTD + lane];
            acc += xv.z * sWt[(k4 * 4 + 2) * OUTD + lane];
            acc += xv.w * sWt[(k4 * 4 + 3) * OUTD + lane];
        }
        Wh[row * OUTD + lane] = acc;
        float vs = acc * as, vd = acc * ad;
#pragma unroll
        for (int m = 1; m < 16; m <<= 1) {
            vs += __shfl_xor(vs, m);
            vd += __shfl_xor(vd, m);
        }
        if ((lane & 15) == 0) {
            int h = lane >> 4;
            asrc[row * NH + h] = vs;
            adst[row * NH + h] = vd;
        }
    }
}

// ---------------- degree histogram ----------------
__global__ void k_hist(const int* __restrict__ ei, int* __restrict__ deg) {
    int e = blockIdx.x * 256 + threadIdx.x;
    if (e < NE) atomicAdd(&deg[ei[NE + e]], 1);
}

// ---------------- 3-phase exclusive scan over deg[NN] ----------------
__global__ __launch_bounds__(256) void k_scan1(const int* __restrict__ deg,
                                               int* __restrict__ offA,
                                               int* __restrict__ bsum) {
    __shared__ int sd[256];
    int b = blockIdx.x, t = threadIdx.x;
    int base = b * 1024 + t * 4;
    int v0 = 0, v1 = 0, v2 = 0, v3 = 0;
    if (base + 0 < NN) v0 = deg[base + 0];
    if (base + 1 < NN) v1 = deg[base + 1];
    if (base + 2 < NN) v2 = deg[base + 2];
    if (base + 3 < NN) v3 = deg[base + 3];
    int s = v0 + v1 + v2 + v3;
    sd[t] = s;
    __syncthreads();
    for (int ofs = 1; ofs < 256; ofs <<= 1) {
        int xv = 0;
        if (t >= ofs) xv = sd[t - ofs];
        __syncthreads();
        sd[t] += xv;
        __syncthreads();
    }
    int excl = sd[t] - s;
    if (base + 0 < NN) offA[base + 0] = excl;
    if (base + 1 < NN) offA[base + 1] = excl + v0;
    if (base + 2 < NN) offA[base + 2] = excl + v0 + v1;
    if (base + 3 < NN) offA[base + 3] = excl + v0 + v1 + v2;
    if (t == 255) bsum[b] = sd[255];
}

__global__ __launch_bounds__(128) void k_scan2(int* __restrict__ bsum) {
    __shared__ int sd[128];
    int t = threadIdx.x;
    int v = (t < NB1) ? bsum[t] : 0;
    sd[t] = v;
    __syncthreads();
    for (int ofs = 1; ofs < 128; ofs <<= 1) {
        int xv = 0;
        if (t >= ofs) xv = sd[t - ofs];
        __syncthreads();
        sd[t] += xv;
        __syncthreads();
    }
    if (t < NB1) bsum[t] = sd[t] - v;  // exclusive
}

__global__ void k_scan3(const int* __restrict__ offA, const int* __restrict__ bsum,
                        int* __restrict__ off, int* __restrict__ pos) {
    int i = blockIdx.x * 256 + threadIdx.x;
    if (i < NN) {
        int v = offA[i] + bsum[i >> 10];
        off[i] = v;
        pos[i] = v;
    }
    if (i == 0) off[NN] = NE;
}

// ---------------- edge scores + slotted max + CSR scatter ----------------
__global__ __launch_bounds__(256) void k_edge(
        const int* __restrict__ ei, const float* __restrict__ ea,
        const float* __restrict__ We, const float* __restrict__ asrc,
        const float* __restrict__ adst, int* __restrict__ pos,
        int* __restrict__ srcs, float* __restrict__ esc4,
        unsigned int* __restrict__ smax) {
    __shared__ float sWe[NH * ED];
    __shared__ float swm[4];
    if (threadIdx.x < NH * ED) sWe[threadIdx.x] = We[threadIdx.x];
    __syncthreads();
    int e = blockIdx.x * 256 + threadIdx.x;
    float lmax = -INFINITY;
    if (e < NE) {
        int s = ei[e], d = ei[NE + e];
        float4 as4 = *(const float4*)(asrc + (long long)s * NH);
        float4 ad4 = *(const float4*)(adst + (long long)d * NH);
        const float4* ea4 = (const float4*)(ea + (long long)e * ED);
        float4 e0 = ea4[0], e1 = ea4[1], e2 = ea4[2], e3 = ea4[3];
        float asv[4] = {as4.x, as4.y, as4.z, as4.w};
        float adv[4] = {ad4.x, ad4.y, ad4.z, ad4.w};
        float sc[4];
#pragma unroll
        for (int h = 0; h < NH; h++) {
            const float* w = sWe + h * ED;
            float t = asv[h] + adv[h];
            t += e0.x * w[0]  + e0.y * w[1]  + e0.z * w[2]  + e0.w * w[3];
            t += e1.x * w[4]  + e1.y * w[5]  + e1.z * w[6]  + e1.w * w[7];
            t += e2.x * w[8]  + e2.y * w[9]  + e2.z * w[10] + e2.w * w[11];
            t += e3.x * w[12] + e3.y * w[13] + e3.z * w[14] + e3.w * w[15];
            t = (t >= 0.f) ? t : 0.2f * t;
            sc[h] = t;
            lmax = fmaxf(lmax, t);
        }
        int p = atomicAdd(&pos[d], 1);
        srcs[p] = s;
        *(float4*)(esc4 + (long long)p * NH) = make_float4(sc[0], sc[1], sc[2], sc[3]);
    }
#pragma unroll
    for (int m = 1; m < 64; m <<= 1) lmax = fmaxf(lmax, __shfl_xor(lmax, m));
    if ((threadIdx.x & 63) == 0) swm[threadIdx.x >> 6] = lmax;
    __syncthreads();
    if (threadIdx.x == 0) {
        float bm = fmaxf(fmaxf(swm[0], swm[1]), fmaxf(swm[2], swm[3]));
        atomicMaxFloat(&smax[blockIdx.x & (NSLOT - 1)], bm);
    }
}

// ---------------- reduce 1024 slots -> gmax ----------------
__global__ __launch_bounds__(1024) void k_gmax(const unsigned int* __restrict__ smax,
                                               unsigned int* __restrict__ gmax) {
    __shared__ float sm[16];
    int t = threadIdx.x;
    float v = __uint_as_float(smax[t]);
#pragma unroll
    for (int m = 1; m < 64; m <<= 1) v = fmaxf(v, __shfl_xor(v, m));
    if ((t & 63) == 0) sm[t >> 6] = v;
    __syncthreads();
    if (t == 0) {
        float g = sm[0];
        for (int i = 1; i < 16; i++) g = fmaxf(g, sm[i]);
        *gmax = __float_as_uint(g);
    }
}

// ---------------- gather: per-node softmax + weighted accumulate + elu ------
__global__ __launch_bounds__(256) void k_gather(
        const int* __restrict__ off, const int* __restrict__ srcs,
        const float* __restrict__ esc4, const float* __restrict__ Wh,
        const unsigned int* __restrict__ gmax, const float* __restrict__ bias,
        float* __restrict__ out) {
    int node = blockIdx.x * 4 + (threadIdx.x >> 6);
    int lane = threadIdx.x & 63;
    if (node >= NN) return;
    int start = off[node], end = off[node + 1];
    float gm = __uint_as_float(*gmax);

    // pass 1: denominator per head
    float4 dsum = make_float4(0.f, 0.f, 0.f, 0.f);
    for (int j = start + lane; j < end; j += 64) {
        float4 sc = ((const float4*)esc4)[j];
        dsum.x += expf(sc.x - gm);
        dsum.y += expf(sc.y - gm);
        dsum.z += expf(sc.z - gm);
        dsum.w += expf(sc.w - gm);
    }
#pragma unroll
    for (int m = 1; m < 64; m <<= 1) {
        dsum.x += __shfl_xor(dsum.x, m);
        dsum.y += __shfl_xor(dsum.y, m);
        dsum.z += __shfl_xor(dsum.z, m);
        dsum.w += __shfl_xor(dsum.w, m);
    }
    int h = lane >> 4;
    float den = (h == 0) ? dsum.x : (h == 1) ? dsum.y : (h == 2) ? dsum.z : dsum.w;
    float rden = 1.0f / (den + 1e-9f);

    // pass 2: accumulate alpha * Wh[s]
    float acc = 0.f;
    for (int j = start; j < end; j++) {
        int s = srcs[j];
        float sc = esc4[j * 4 + h];
        acc += Wh[(long long)s * OUTD + lane] * (expf(sc - gm) * rden);
    }
    float v = acc + bias[lane];
    out[(long long)node * OUTD + lane] = (v > 0.f) ? v : expm1f(v);
}

extern "C" void kernel_launch(void* const* d_in, const int* in_sizes, int n_in,
                              void* d_out, int out_size, void* d_ws, size_t ws_size,
                              hipStream_t stream) {
    const float* x     = (const float*)d_in[0];   // [NN,128]
    const int*   ei    = (const int*)d_in[1];     // [2,NE]
    const float* ea    = (const float*)d_in[2];   // [NE,16]
    const float* Wn    = (const float*)d_in[3];   // [64,128]
    const float* We    = (const float*)d_in[4];   // [4,16]
    const float* att_s = (const float*)d_in[5];   // 64
    const float* att_d = (const float*)d_in[6];   // 64
    const float* bias  = (const float*)d_in[7];   // 64
    float* out = (float*)d_out;

    float* ws   = (float*)d_ws;
    float* Wh   = ws;                                   // NN*64 f
    float* asrc = Wh + (size_t)NN * OUTD;               // NN*4 f
    float* adst = asrc + (size_t)NN * NH;               // NN*4 f
    float* esc4 = adst + (size_t)NN * NH;               // NE*4 f (dest-sorted scores)
    int*   srcs = (int*)(esc4 + (size_t)NE * NH);       // NE i
    int*   deg  = srcs + (size_t)NE;                    // NN i
    int*   offA = deg + NN;                             // NN i
    int*   off  = offA + NN;                            // NN+1 i
    int*   pos  = off + NN + 1;                         // NN i
    int*   bsum = pos + NN;                             // 128 i
    unsigned int* smax = (unsigned int*)(bsum + 128);   // 1024
    unsigned int* gmax = smax + NSLOT;                  // 1

    k_zero<<<(NN + 255) / 256, 256, 0, stream>>>(deg, smax);
    k_node<<<(NN + 15) / 16, 256, 0, stream>>>(x, Wn, att_s, att_d, Wh, asrc, adst);
    k_hist<<<(NE + 255) / 256, 256, 0, stream>>>(ei, deg);
    k_scan1<<<NB1, 256, 0, stream>>>(deg, offA, bsum);
    k_scan2<<<1, 128, 0, stream>>>(bsum);
    k_scan3<<<(NN + 255) / 256, 256, 0, stream>>>(offA, bsum, off, pos);
    k_edge<<<(NE + 255) / 256, 256, 0, stream>>>(ei, ea, We, asrc, adst, pos, srcs, esc4, smax);
    k_gmax<<<1, NSLOT, 0, stream>>>(smax, gmax);
    k_gather<<<(NN + 3) / 4, 256, 0, stream>>>(off, srcs, esc4, Wh, gmax, bias, out);
}

// Round 4
// 523.999 us; speedup vs baseline: 4.2474x; 1.1720x over previous
//
#include <hip/hip_runtime.h>
#include <math.h>

#define NN 100000
#define NE 1600000
#define IND 128
#define OUTD 64
#define ED 16
#define NH 4
#define HD 16
#define NB1 98      // ceil(NN/1024) for scan phase 1
#define NSLOT 1024  // gmax reduction slots

static __device__ __forceinline__ void atomicMaxFloat(unsigned int* addr, float v) {
    if (v >= 0.f) atomicMax((int*)addr, __float_as_int(v));
    else          atomicMin(addr, (unsigned int)__float_as_int(v));
}

// ---------------- zero degree histogram, init gmax slots ----------------
__global__ void k_zero(int* __restrict__ deg, unsigned int* __restrict__ smax) {
    int i = blockIdx.x * 256 + threadIdx.x;
    if (i < NN) deg[i] = 0;
    if (i < NSLOT) smax[i] = 0xFF800000u;  // -inf
}

// ---------------- node GEMM + attention scalars --------
__global__ __launch_bounds__(256) void k_node(
        const float* __restrict__ x, const float* __restrict__ Wn,
        const float* __restrict__ att_s, const float* __restrict__ att_d,
        float* __restrict__ Wh, float* __restrict__ asrc, float* __restrict__ adst) {
    __shared__ float sWt[IND * OUTD];   // 32 KB, [k][c]
    __shared__ float sx[16][IND];       // 8 KB
    int tid = threadIdx.x;
    {
        int c = tid & 63;
        for (int k4 = tid >> 6; k4 < IND / 4; k4 += 4) {
            float4 v = ((const float4*)Wn)[c * (IND / 4) + k4];
            sWt[(k4 * 4 + 0) * OUTD + c] = v.x;
            sWt[(k4 * 4 + 1) * OUTD + c] = v.y;
            sWt[(k4 * 4 + 2) * OUTD + c] = v.z;
            sWt[(k4 * 4 + 3) * OUTD + c] = v.w;
        }
    }
    long long rowBase = (long long)blockIdx.x * 16;
    for (int i = tid; i < 16 * (IND / 4); i += 256) {
        int r = i >> 5, k4 = i & 31;
        long long row = rowBase + r;
        float4 v = make_float4(0.f, 0.f, 0.f, 0.f);
        if (row < NN) v = ((const float4*)x)[row * (IND / 4) + k4];
        ((float4*)sx)[r * (IND / 4) + k4] = v;
    }
    __syncthreads();

    int wave = tid >> 6, lane = tid & 63;
    float as = att_s[lane];
    float ad = att_d[lane];
    for (int rr = 0; rr < 4; rr++) {
        long long row = rowBase + wave * 4 + rr;
        if (row >= NN) break;
        const float4* sx4 = (const float4*)&sx[wave * 4 + rr][0];
        float acc = 0.f;
#pragma unroll
        for (int k4 = 0; k4 < IND / 4; k4++) {
            float4 xv = sx4[k4];
            acc += xv.x * sWt[(k4 * 4 + 0) * OUTD + lane];
            acc += xv.y * sWt[(k4 * 4 + 1) * OUTD + lane];
            acc += xv.z * sWt[(k4 * 4 + 2) * OUTD + lane];
            acc += xv.w * sWt[(k4 * 4 + 3) * OUTD + lane];
        }
        Wh[row * OUTD + lane] = acc;
        float vs = acc * as, vd = acc * ad;
#pragma unroll
        for (int m = 1; m < 16; m <<= 1) {
            vs += __shfl_xor(vs, m);
            vd += __shfl_xor(vd, m);
        }
        if ((lane & 15) == 0) {
            int h = lane >> 4;
            asrc[row * NH + h] = vs;
            adst[row * NH + h] = vd;
        }
    }
}

// ---------------- degree histogram ----------------
__global__ void k_hist(const int* __restrict__ ei, int* __restrict__ deg) {
    int e = blockIdx.x * 256 + threadIdx.x;
    if (e < NE) atomicAdd(&deg[ei[NE + e]], 1);
}

// ---------------- 3-phase exclusive scan over deg[NN] ----------------
__global__ __launch_bounds__(256) void k_scan1(const int* __restrict__ deg,
                                               int* __restrict__ offA,
                                               int* __restrict__ bsum) {
    __shared__ int sd[256];
    int b = blockIdx.x, t = threadIdx.x;
    int base = b * 1024 + t * 4;
    int v0 = 0, v1 = 0, v2 = 0, v3 = 0;
    if (base + 0 < NN) v0 = deg[base + 0];
    if (base + 1 < NN) v1 = deg[base + 1];
    if (base + 2 < NN) v2 = deg[base + 2];
    if (base + 3 < NN) v3 = deg[base + 3];
    int s = v0 + v1 + v2 + v3;
    sd[t] = s;
    __syncthreads();
    for (int ofs = 1; ofs < 256; ofs <<= 1) {
        int xv = 0;
        if (t >= ofs) xv = sd[t - ofs];
        __syncthreads();
        sd[t] += xv;
        __syncthreads();
    }
    int excl = sd[t] - s;
    if (base + 0 < NN) offA[base + 0] = excl;
    if (base + 1 < NN) offA[base + 1] = excl + v0;
    if (base + 2 < NN) offA[base + 2] = excl + v0 + v1;
    if (base + 3 < NN) offA[base + 3] = excl + v0 + v1 + v2;
    if (t == 255) bsum[b] = sd[255];
}

__global__ __launch_bounds__(128) void k_scan2(int* __restrict__ bsum) {
    __shared__ int sd[128];
    int t = threadIdx.x;
    int v = (t < NB1) ? bsum[t] : 0;
    sd[t] = v;
    __syncthreads();
    for (int ofs = 1; ofs < 128; ofs <<= 1) {
        int xv = 0;
        if (t >= ofs) xv = sd[t - ofs];
        __syncthreads();
        sd[t] += xv;
        __syncthreads();
    }
    if (t < NB1) bsum[t] = sd[t] - v;  // exclusive
}

__global__ void k_scan3(const int* __restrict__ offA, const int* __restrict__ bsum,
                        int* __restrict__ off, int* __restrict__ pos) {
    int i = blockIdx.x * 256 + threadIdx.x;
    if (i < NN) {
        int v = offA[i] + bsum[i >> 10];
        off[i] = v;
        pos[i] = v;
    }
    if (i == 0) off[NN] = NE;
}

// ---------------- edge scores + slotted max + CSR scatter ----------------
__global__ __launch_bounds__(256) void k_edge(
        const int* __restrict__ ei, const float* __restrict__ ea,
        const float* __restrict__ We, const float* __restrict__ asrc,
        const float* __restrict__ adst, int* __restrict__ pos,
        int* __restrict__ srcs, float* __restrict__ esc4,
        unsigned int* __restrict__ smax) {
    __shared__ float sWe[NH * ED];
    __shared__ float swm[4];
    if (threadIdx.x < NH * ED) sWe[threadIdx.x] = We[threadIdx.x];
    __syncthreads();
    int e = blockIdx.x * 256 + threadIdx.x;
    float lmax = -INFINITY;
    if (e < NE) {
        int s = ei[e], d = ei[NE + e];
        float4 as4 = *(const float4*)(asrc + (long long)s * NH);
        float4 ad4 = *(const float4*)(adst + (long long)d * NH);
        const float4* ea4 = (const float4*)(ea + (long long)e * ED);
        float4 e0 = ea4[0], e1 = ea4[1], e2 = ea4[2], e3 = ea4[3];
        float asv[4] = {as4.x, as4.y, as4.z, as4.w};
        float adv[4] = {ad4.x, ad4.y, ad4.z, ad4.w};
        float sc[4];
#pragma unroll
        for (int h = 0; h < NH; h++) {
            const float* w = sWe + h * ED;
            float t = asv[h] + adv[h];
            t += e0.x * w[0]  + e0.y * w[1]  + e0.z * w[2]  + e0.w * w[3];
            t += e1.x * w[4]  + e1.y * w[5]  + e1.z * w[6]  + e1.w * w[7];
            t += e2.x * w[8]  + e2.y * w[9]  + e2.z * w[10] + e2.w * w[11];
            t += e3.x * w[12] + e3.y * w[13] + e3.z * w[14] + e3.w * w[15];
            t = (t >= 0.f) ? t : 0.2f * t;
            sc[h] = t;
            lmax = fmaxf(lmax, t);
        }
        int p = atomicAdd(&pos[d], 1);
        srcs[p] = s;
        *(float4*)(esc4 + (long long)p * NH) = make_float4(sc[0], sc[1], sc[2], sc[3]);
    }
#pragma unroll
    for (int m = 1; m < 64; m <<= 1) lmax = fmaxf(lmax, __shfl_xor(lmax, m));
    if ((threadIdx.x & 63) == 0) swm[threadIdx.x >> 6] = lmax;
    __syncthreads();
    if (threadIdx.x == 0) {
        float bm = fmaxf(fmaxf(swm[0], swm[1]), fmaxf(swm[2], swm[3]));
        atomicMaxFloat(&smax[blockIdx.x & (NSLOT - 1)], bm);
    }
}

// ---------------- reduce 1024 slots -> gmax ----------------
__global__ __launch_bounds__(1024) void k_gmax(const unsigned int* __restrict__ smax,
                                               unsigned int* __restrict__ gmax) {
    __shared__ float sm[16];
    int t = threadIdx.x;
    float v = __uint_as_float(smax[t]);
#pragma unroll
    for (int m = 1; m < 64; m <<= 1) v = fmaxf(v, __shfl_xor(v, m));
    if ((t & 63) == 0) sm[t >> 6] = v;
    __syncthreads();
    if (t == 0) {
        float g = sm[0];
        for (int i = 1; i < 16; i++) g = fmaxf(g, sm[i]);
        *gmax = __float_as_uint(g);
    }
}

// ---------------- exp(sc - gmax) in place over esc4 ----------------
__global__ __launch_bounds__(256) void k_exp(float* __restrict__ esc4,
                                             const unsigned int* __restrict__ gmax) {
    int i = blockIdx.x * 256 + threadIdx.x;  // float4 index over NE
    if (i >= NE) return;
    float gm = __uint_as_float(*gmax);
    float4 v = ((float4*)esc4)[i];
    v.x = expf(v.x - gm);
    v.y = expf(v.y - gm);
    v.z = expf(v.z - gm);
    v.w = expf(v.w - gm);
    ((float4*)esc4)[i] = v;
}

// ---------------- gather: single-pass weighted accumulate + softmax + elu ---
// wave per node; 4 groups of 16 lanes; group g handles edges j = start+g, +4...
// lane holds channels c16*4..c16*4+3 (float4); head h = c16>>2.
__global__ __launch_bounds__(256) void k_gather(
        const int* __restrict__ off, const int* __restrict__ srcs,
        const float* __restrict__ ex4, const float* __restrict__ Wh,
        const float* __restrict__ bias, float* __restrict__ out) {
    int node = blockIdx.x * 4 + (threadIdx.x >> 6);
    int lane = threadIdx.x & 63;
    if (node >= NN) return;
    int start = off[node], end = off[node + 1];
    int g = lane >> 4;       // edge group
    int c16 = lane & 15;     // channel quad
    int h = c16 >> 2;        // head

    float4 acc = make_float4(0.f, 0.f, 0.f, 0.f);
    float dsum = 0.f;
#pragma unroll 2
    for (int j = start + g; j < end; j += 4) {
        int s = srcs[j];
        float ex = ex4[j * 4 + h];
        float4 w = *(const float4*)(Wh + (long long)s * OUTD + c16 * 4);
        acc.x += ex * w.x;
        acc.y += ex * w.y;
        acc.z += ex * w.z;
        acc.w += ex * w.w;
        dsum += ex;
    }
    // combine the 4 edge-groups (lanes l, l+16, l+32, l+48 share c16)
#pragma unroll
    for (int m = 16; m < 64; m <<= 1) {
        acc.x += __shfl_xor(acc.x, m);
        acc.y += __shfl_xor(acc.y, m);
        acc.z += __shfl_xor(acc.z, m);
        acc.w += __shfl_xor(acc.w, m);
        dsum += __shfl_xor(dsum, m);
    }
    if (g == 0) {
        float rden = 1.0f / (dsum + 1e-9f);
        const float4 b4 = *(const float4*)(bias + c16 * 4);
        float4 v;
        v.x = acc.x * rden + b4.x;
        v.y = acc.y * rden + b4.y;
        v.z = acc.z * rden + b4.z;
        v.w = acc.w * rden + b4.w;
        v.x = (v.x > 0.f) ? v.x : expm1f(v.x);
        v.y = (v.y > 0.f) ? v.y : expm1f(v.y);
        v.z = (v.z > 0.f) ? v.z : expm1f(v.z);
        v.w = (v.w > 0.f) ? v.w : expm1f(v.w);
        *(float4*)(out + (long long)node * OUTD + c16 * 4) = v;
    }
}

extern "C" void kernel_launch(void* const* d_in, const int* in_sizes, int n_in,
                              void* d_out, int out_size, void* d_ws, size_t ws_size,
                              hipStream_t stream) {
    const float* x     = (const float*)d_in[0];   // [NN,128]
    const int*   ei    = (const int*)d_in[1];     // [2,NE]
    const float* ea    = (const float*)d_in[2];   // [NE,16]
    const float* Wn    = (const float*)d_in[3];   // [64,128]
    const float* We    = (const float*)d_in[4];   // [4,16]
    const float* att_s = (const float*)d_in[5];   // 64
    const float* att_d = (const float*)d_in[6];   // 64
    const float* bias  = (const float*)d_in[7];   // 64
    float* out = (float*)d_out;

    float* ws   = (float*)d_ws;
    float* Wh   = ws;                                   // NN*64 f
    float* asrc = Wh + (size_t)NN * OUTD;               // NN*4 f
    float* adst = asrc + (size_t)NN * NH;               // NN*4 f
    float* esc4 = adst + (size_t)NN * NH;               // NE*4 f (dest-sorted scores/ex)
    int*   srcs = (int*)(esc4 + (size_t)NE * NH);       // NE i
    int*   deg  = srcs + (size_t)NE;                    // NN i
    int*   offA = deg + NN;                             // NN i
    int*   off  = offA + NN;                            // NN+1 i
    int*   pos  = off + NN + 1;                         // NN i
    int*   bsum = pos + NN;                             // 128 i
    unsigned int* smax = (unsigned int*)(bsum + 128);   // 1024
    unsigned int* gmax = smax + NSLOT;                  // 1

    k_zero<<<(NN + 255) / 256, 256, 0, stream>>>(deg, smax);
    k_node<<<(NN + 15) / 16, 256, 0, stream>>>(x, Wn, att_s, att_d, Wh, asrc, adst);
    k_hist<<<(NE + 255) / 256, 256, 0, stream>>>(ei, deg);
    k_scan1<<<NB1, 256, 0, stream>>>(deg, offA, bsum);
    k_scan2<<<1, 128, 0, stream>>>(bsum);
    k_scan3<<<(NN + 255) / 256, 256, 0, stream>>>(offA, bsum, off, pos);
    k_edge<<<(NE + 255) / 256, 256, 0, stream>>>(ei, ea, We, asrc, adst, pos, srcs, esc4, smax);
    k_gmax<<<1, NSLOT, 0, stream>>>(smax, gmax);
    k_exp<<<(NE + 255) / 256, 256, 0, stream>>>(esc4, gmax);
    k_gather<<<(NN + 3) / 4, 256, 0, stream>>>(off, srcs, esc4, Wh, bias, out);
}

// Round 5
// 517.652 us; speedup vs baseline: 4.2995x; 1.0123x over previous
//
#include <hip/hip_runtime.h>
#include <math.h>

#define NN 100000
#define NE 1600000
#define NEH 800000  // NE/2
#define IND 128
#define OUTD 64
#define ED 16
#define NH 4
#define HD 16
#define NB1 98      // ceil(NN/1024) for scan phase 1
#define NSLOT 1024  // gmax reduction slots

static __device__ __forceinline__ void atomicMaxFloat(unsigned int* addr, float v) {
    if (v >= 0.f) atomicMax((int*)addr, __float_as_int(v));
    else          atomicMin(addr, (unsigned int)__float_as_int(v));
}

// ---------------- zero degree histogram, init gmax slots ----------------
__global__ void k_zero(int* __restrict__ deg, unsigned int* __restrict__ smax) {
    int i = blockIdx.x * 256 + threadIdx.x;
    if (i < NN) deg[i] = 0;
    if (i < NSLOT) smax[i] = 0xFF800000u;  // -inf
}

// ---------------- node GEMM + attention scalars --------
__global__ __launch_bounds__(256) void k_node(
        const float* __restrict__ x, const float* __restrict__ Wn,
        const float* __restrict__ att_s, const float* __restrict__ att_d,
        float* __restrict__ Wh, float* __restrict__ asrc, float* __restrict__ adst) {
    __shared__ float sWt[IND * OUTD];   // 32 KB, [k][c]
    __shared__ float sx[16][IND];       // 8 KB
    int tid = threadIdx.x;
    {
        int c = tid & 63;
        for (int k4 = tid >> 6; k4 < IND / 4; k4 += 4) {
            float4 v = ((const float4*)Wn)[c * (IND / 4) + k4];
            sWt[(k4 * 4 + 0) * OUTD + c] = v.x;
            sWt[(k4 * 4 + 1) * OUTD + c] = v.y;
            sWt[(k4 * 4 + 2) * OUTD + c] = v.z;
            sWt[(k4 * 4 + 3) * OUTD + c] = v.w;
        }
    }
    long long rowBase = (long long)blockIdx.x * 16;
    for (int i = tid; i < 16 * (IND / 4); i += 256) {
        int r = i >> 5, k4 = i & 31;
        long long row = rowBase + r;
        float4 v = make_float4(0.f, 0.f, 0.f, 0.f);
        if (row < NN) v = ((const float4*)x)[row * (IND / 4) + k4];
        ((float4*)sx)[r * (IND / 4) + k4] = v;
    }
    __syncthreads();

    int wave = tid >> 6, lane = tid & 63;
    float as = att_s[lane];
    float ad = att_d[lane];
    for (int rr = 0; rr < 4; rr++) {
        long long row = rowBase + wave * 4 + rr;
        if (row >= NN) break;
        const float4* sx4 = (const float4*)&sx[wave * 4 + rr][0];
        float acc = 0.f;
#pragma unroll
        for (int k4 = 0; k4 < IND / 4; k4++) {
            float4 xv = sx4[k4];
            acc += xv.x * sWt[(k4 * 4 + 0) * OUTD + lane];
            acc += xv.y * sWt[(k4 * 4 + 1) * OUTD + lane];
            acc += xv.z * sWt[(k4 * 4 + 2) * OUTD + lane];
            acc += xv.w * sWt[(k4 * 4 + 3) * OUTD + lane];
        }
        Wh[row * OUTD + lane] = acc;
        float vs = acc * as, vd = acc * ad;
#pragma unroll
        for (int m = 1; m < 16; m <<= 1) {
            vs += __shfl_xor(vs, m);
            vd += __shfl_xor(vd, m);
        }
        if ((lane & 15) == 0) {
            int h = lane >> 4;
            asrc[row * NH + h] = vs;
            adst[row * NH + h] = vd;
        }
    }
}

// ---------------- degree histogram ----------------
__global__ void k_hist(const int* __restrict__ ei, int* __restrict__ deg) {
    int e = blockIdx.x * 256 + threadIdx.x;
    if (e < NE) atomicAdd(&deg[ei[NE + e]], 1);
}

// ---------------- 3-phase exclusive scan over deg[NN] ----------------
__global__ __launch_bounds__(256) void k_scan1(const int* __restrict__ deg,
                                               int* __restrict__ offA,
                                               int* __restrict__ bsum) {
    __shared__ int sd[256];
    int b = blockIdx.x, t = threadIdx.x;
    int base = b * 1024 + t * 4;
    int v0 = 0, v1 = 0, v2 = 0, v3 = 0;
    if (base + 0 < NN) v0 = deg[base + 0];
    if (base + 1 < NN) v1 = deg[base + 1];
    if (base + 2 < NN) v2 = deg[base + 2];
    if (base + 3 < NN) v3 = deg[base + 3];
    int s = v0 + v1 + v2 + v3;
    sd[t] = s;
    __syncthreads();
    for (int ofs = 1; ofs < 256; ofs <<= 1) {
        int xv = 0;
        if (t >= ofs) xv = sd[t - ofs];
        __syncthreads();
        sd[t] += xv;
        __syncthreads();
    }
    int excl = sd[t] - s;
    if (base + 0 < NN) offA[base + 0] = excl;
    if (base + 1 < NN) offA[base + 1] = excl + v0;
    if (base + 2 < NN) offA[base + 2] = excl + v0 + v1;
    if (base + 3 < NN) offA[base + 3] = excl + v0 + v1 + v2;
    if (t == 255) bsum[b] = sd[255];
}

__global__ __launch_bounds__(128) void k_scan2(int* __restrict__ bsum) {
    __shared__ int sd[128];
    int t = threadIdx.x;
    int v = (t < NB1) ? bsum[t] : 0;
    sd[t] = v;
    __syncthreads();
    for (int ofs = 1; ofs < 128; ofs <<= 1) {
        int xv = 0;
        if (t >= ofs) xv = sd[t - ofs];
        __syncthreads();
        sd[t] += xv;
        __syncthreads();
    }
    if (t < NB1) bsum[t] = sd[t] - v;  // exclusive
}

__global__ void k_scan3(const int* __restrict__ offA, const int* __restrict__ bsum,
                        int* __restrict__ off, int* __restrict__ pos) {
    int i = blockIdx.x * 256 + threadIdx.x;
    if (i < NN) {
        int v = offA[i] + bsum[i >> 10];
        off[i] = v;
        pos[i] = v;
    }
    if (i == 0) off[NN] = NE;
}

// ---------------- edge scores + slotted max + packed CSR scatter ----------
// record @ rec + 8*p floats: [sc0 sc1 sc2 sc3 | src ... pad] (32 B)
__global__ __launch_bounds__(256) void k_edge(
        const int* __restrict__ ei, const float* __restrict__ ea,
        const float* __restrict__ We, const float* __restrict__ asrc,
        const float* __restrict__ adst, int* __restrict__ pos,
        float* __restrict__ rec, unsigned int* __restrict__ smax) {
    __shared__ float sWe[NH * ED];
    __shared__ float swm[4];
    if (threadIdx.x < NH * ED) sWe[threadIdx.x] = We[threadIdx.x];
    __syncthreads();
    int e0 = blockIdx.x * 256 + threadIdx.x;
    float lmax = -INFINITY;
#pragma unroll
    for (int half = 0; half < 2; half++) {
        int e = e0 + half * NEH;
        int s = ei[e], d = ei[NE + e];
        float4 as4 = *(const float4*)(asrc + (long long)s * NH);
        float4 ad4 = *(const float4*)(adst + (long long)d * NH);
        const float4* ea4 = (const float4*)(ea + (long long)e * ED);
        float4 q0 = ea4[0], q1 = ea4[1], q2 = ea4[2], q3 = ea4[3];
        float asv[4] = {as4.x, as4.y, as4.z, as4.w};
        float adv[4] = {ad4.x, ad4.y, ad4.z, ad4.w};
        float sc[4];
#pragma unroll
        for (int h = 0; h < NH; h++) {
            const float* w = sWe + h * ED;
            float t = asv[h] + adv[h];
            t += q0.x * w[0]  + q0.y * w[1]  + q0.z * w[2]  + q0.w * w[3];
            t += q1.x * w[4]  + q1.y * w[5]  + q1.z * w[6]  + q1.w * w[7];
            t += q2.x * w[8]  + q2.y * w[9]  + q2.z * w[10] + q2.w * w[11];
            t += q3.x * w[12] + q3.y * w[13] + q3.z * w[14] + q3.w * w[15];
            t = (t >= 0.f) ? t : 0.2f * t;
            sc[h] = t;
            lmax = fmaxf(lmax, t);
        }
        int p = atomicAdd(&pos[d], 1);
        float* rp = rec + (long long)p * 8;
        *(float4*)rp = make_float4(sc[0], sc[1], sc[2], sc[3]);
        *(int*)(rp + 4) = s;
    }
#pragma unroll
    for (int m = 1; m < 64; m <<= 1) lmax = fmaxf(lmax, __shfl_xor(lmax, m));
    if ((threadIdx.x & 63) == 0) swm[threadIdx.x >> 6] = lmax;
    __syncthreads();
    if (threadIdx.x == 0) {
        float bm = fmaxf(fmaxf(swm[0], swm[1]), fmaxf(swm[2], swm[3]));
        atomicMaxFloat(&smax[blockIdx.x & (NSLOT - 1)], bm);
    }
}

// ---------------- reduce 1024 slots -> gmax ----------------
__global__ __launch_bounds__(1024) void k_gmax(const unsigned int* __restrict__ smax,
                                               unsigned int* __restrict__ gmax) {
    __shared__ float sm[16];
    int t = threadIdx.x;
    float v = __uint_as_float(smax[t]);
#pragma unroll
    for (int m = 1; m < 64; m <<= 1) v = fmaxf(v, __shfl_xor(v, m));
    if ((t & 63) == 0) sm[t >> 6] = v;
    __syncthreads();
    if (t == 0) {
        float g = sm[0];
        for (int i = 1; i < 16; i++) g = fmaxf(g, sm[i]);
        *gmax = __float_as_uint(g);
    }
}

// ---------------- gather: single-pass softmax + accumulate + elu ----------
// wave per node; 4 groups of 16 lanes; group g handles edges j = start+g, +4...
// lane holds channels c16*4..c16*4+3 (float4); head h = c16>>2.
__global__ __launch_bounds__(256) void k_gather(
        const int* __restrict__ off, const float* __restrict__ rec,
        const float* __restrict__ Wh, const unsigned int* __restrict__ gmax,
        const float* __restrict__ bias, float* __restrict__ out) {
    int node = blockIdx.x * 4 + (threadIdx.x >> 6);
    int lane = threadIdx.x & 63;
    if (node >= NN) return;
    int start = off[node], end = off[node + 1];
    float gm = __uint_as_float(*gmax);
    int g = lane >> 4;       // edge group
    int c16 = lane & 15;     // channel quad
    int h = c16 >> 2;        // head

    float4 acc = make_float4(0.f, 0.f, 0.f, 0.f);
    float dsum = 0.f;
#pragma unroll 2
    for (int j = start + g; j < end; j += 4) {
        const float* rp = rec + (long long)j * 8;
        float4 sc = *(const float4*)rp;            // 16-lane broadcast
        int s = *(const int*)(rp + 4);
        float sch = (h == 0) ? sc.x : (h == 1) ? sc.y : (h == 2) ? sc.z : sc.w;
        float ex = expf(sch - gm);
        float4 w = *(const float4*)(Wh + (long long)s * OUTD + c16 * 4);
        acc.x += ex * w.x;
        acc.y += ex * w.y;
        acc.z += ex * w.z;
        acc.w += ex * w.w;
        dsum += ex;
    }
    // combine the 4 edge-groups (lanes l, l+16, l+32, l+48 share c16)
#pragma unroll
    for (int m = 16; m < 64; m <<= 1) {
        acc.x += __shfl_xor(acc.x, m);
        acc.y += __shfl_xor(acc.y, m);
        acc.z += __shfl_xor(acc.z, m);
        acc.w += __shfl_xor(acc.w, m);
        dsum += __shfl_xor(dsum, m);
    }
    if (g == 0) {
        float rden = 1.0f / (dsum + 1e-9f);
        const float4 b4 = *(const float4*)(bias + c16 * 4);
        float4 v;
        v.x = acc.x * rden + b4.x;
        v.y = acc.y * rden + b4.y;
        v.z = acc.z * rden + b4.z;
        v.w = acc.w * rden + b4.w;
        v.x = (v.x > 0.f) ? v.x : expm1f(v.x);
        v.y = (v.y > 0.f) ? v.y : expm1f(v.y);
        v.z = (v.z > 0.f) ? v.z : expm1f(v.z);
        v.w = (v.w > 0.f) ? v.w : expm1f(v.w);
        *(float4*)(out + (long long)node * OUTD + c16 * 4) = v;
    }
}

extern "C" void kernel_launch(void* const* d_in, const int* in_sizes, int n_in,
                              void* d_out, int out_size, void* d_ws, size_t ws_size,
                              hipStream_t stream) {
    const float* x     = (const float*)d_in[0];   // [NN,128]
    const int*   ei    = (const int*)d_in[1];     // [2,NE]
    const float* ea    = (const float*)d_in[2];   // [NE,16]
    const float* Wn    = (const float*)d_in[3];   // [64,128]
    const float* We    = (const float*)d_in[4];   // [4,16]
    const float* att_s = (const float*)d_in[5];   // 64
    const float* att_d = (const float*)d_in[6];   // 64
    const float* bias  = (const float*)d_in[7];   // 64
    float* out = (float*)d_out;

    float* ws   = (float*)d_ws;
    float* Wh   = ws;                                   // NN*64 f
    float* asrc = Wh + (size_t)NN * OUTD;               // NN*4 f
    float* adst = asrc + (size_t)NN * NH;               // NN*4 f
    float* rec  = adst + (size_t)NN * NH;               // NE*8 f (packed records)
    int*   deg  = (int*)(rec + (size_t)NE * 8);         // NN i
    int*   offA = deg + NN;                             // NN i
    int*   off  = offA + NN;                            // NN+1 i
    int*   pos  = off + NN + 1;                         // NN i
    int*   bsum = pos + NN;                             // 128 i
    unsigned int* smax = (unsigned int*)(bsum + 128);   // 1024
    unsigned int* gmax = smax + NSLOT;                  // 1

    k_zero<<<(NN + 255) / 256, 256, 0, stream>>>(deg, smax);
    k_node<<<(NN + 15) / 16, 256, 0, stream>>>(x, Wn, att_s, att_d, Wh, asrc, adst);
    k_hist<<<(NE + 255) / 256, 256, 0, stream>>>(ei, deg);
    k_scan1<<<NB1, 256, 0, stream>>>(deg, offA, bsum);
    k_scan2<<<1, 128, 0, stream>>>(bsum);
    k_scan3<<<(NN + 255) / 256, 256, 0, stream>>>(offA, bsum, off, pos);
    k_edge<<<NEH / 256, 256, 0, stream>>>(ei, ea, We, asrc, adst, pos, rec, smax);
    k_gmax<<<1, NSLOT, 0, stream>>>(smax, gmax);
    k_gather<<<(NN + 3) / 4, 256, 0, stream>>>(off, rec, Wh, gmax, bias, out);
}